// Round 18
// baseline (431.042 us; speedup 1.0000x reference)
//
#include <hip/hip_runtime.h>
#include <hip/hip_bf16.h>
#include <stdint.h>

typedef short bhalf8 __attribute__((ext_vector_type(8)));
typedef float facc4 __attribute__((ext_vector_type(4)));
typedef unsigned int uintv2 __attribute__((ext_vector_type(2)));

static __device__ __forceinline__ unsigned short f2bfu(float f) {
  return __builtin_bit_cast(unsigned short, __float2bfloat16(f));
}

// ---------------------------------------------------------------------------
// prep: sample conv weights w = loc + L@eps (L = tril(-1)+softplus(diag)*I)
// bf16 layout wt[a=kh*3+kw][kc=i>>5][o][i&31] (R12-proven), bias.
// ---------------------------------------------------------------------------
__global__ void prep_kernel(const float* __restrict__ wloc,
                            const float* __restrict__ wL,
                            const float* __restrict__ eps_w,
                            const float* __restrict__ bloc,
                            const float* __restrict__ bro,
                            const float* __restrict__ eps_b,
                            short* __restrict__ wt, float* __restrict__ bias) {
  int t = blockIdx.x * 256 + threadIdx.x;  // t = o*64 + i
  int o = t >> 6, i = t & 63;
  int kc = i >> 5, il = i & 31;
  const float* Lp = wL + (size_t)t * 81;
  const float* ep = eps_w + (size_t)t * 9;
  const float* lp = wloc + (size_t)t * 9;
  float e[9];
#pragma unroll
  for (int b = 0; b < 9; ++b) e[b] = ep[b];
#pragma unroll
  for (int a = 0; a < 9; ++a) {
    float s = lp[a];
    for (int b = 0; b < a; ++b) s += Lp[a * 9 + b] * e[b];
    float d = Lp[a * 9 + a];
    float sp = (d > 20.f) ? d : log1pf(expf(d));
    s += sp * e[a];
    wt[((a * 2 + kc) * 64 + o) * 32 + il] = (short)f2bfu(s);
  }
  if (t < 64) {
    float d = bro[t];
    float sp = (d > 20.f) ? d : log1pf(expf(d));
    bias[t] = bloc[t] + eps_b[t] * sp;
  }
}

// ---------------------------------------------------------------------------
// 14-round strip-sweep fused conv. Grid 1024 = 32 strips(7 rows) x 32 n =
// EXACTLY 2 uniform generations of 512 resident blocks (zero tail quant,
// zero length imbalance -- the R13 failure modes). Block = 7 waves (448
// thr), sweeps wc=0..6 x ic (palindromic: restage wt only at even-rr
// boundaries). Per round: x [9r][4g][34cc][8ch] bf16 19.6 KB, dbuf; wt
// 36.9 KB single. LDS 76.0 KB -> 2 blocks/CU. T14 reg-staging: round rr+1
// x loads ISSUE before round-rr MFMA; cvt+ds_write after the reads-done
// barrier. Stores spread across the 7 odd rounds (issue never bursty).
// Prologue paid once per 14 rounds (vs once per 2 in R15).
// ---------------------------------------------------------------------------
#define XBUF 9792  // shorts per x buffer ([9][4][34] chunks * 8)

#define LD1(cj, i)                                                    \
  ((hok && (w_in0 + (i)) >= 0 && (w_in0 + (i)) < 224)                 \
       ? cbase[(size_t)(cj)*50176 + w_in0 + (i)]                      \
       : 0.f)

__global__ __launch_bounds__(448, 4) void conv_sweep_kernel(
    const float* __restrict__ x, const short* __restrict__ wtg,
    const float* __restrict__ bias, float* __restrict__ out) {
  extern __shared__ short smem[];
  short* lds_x = smem;           // 2 * 9792 shorts = 39168 B
  short* lds_w = smem + 19584;   // 2304 chunks * 8 = 18432 shorts = 36864 B

  int b0 = blockIdx.x;
  int b = (b0 & 7) * 128 + (b0 >> 3);  // bijective: 1024 % 8 == 0
  int ht = b & 31, n = b >> 5;         // consecutive b -> adjacent strips
  int h0 = ht * 7;
  int t = threadIdx.x, lane = t & 63, wv = t >> 6;  // wv 0..6
  int l15 = lane & 15, l4 = lane >> 4;

  // ---- x staging: 648 units of 4px x 4ch f32 (u = t + k*448) ----
#define LOADX(V, wc_, ic_)                                                  \
  do {                                                                      \
    _Pragma("unroll") for (int k = 0; k < 2; ++k) {                         \
      int u = t + k * 448;                                                  \
      if (u < 648) {                                                        \
        int chg = u & 7, tmp = u >> 3;                                      \
        int ccg = tmp % 9, r = tmp / 9;                                     \
        int h_in = h0 - 1 + r;                                              \
        bool hok = (h_in >= 0) & (h_in < 224);                              \
        int w_in0 = (wc_)*32 - 1 + ccg * 4;                                 \
        const float* cbase =                                                \
            x + ((size_t)(n * 64 + (ic_)*32 + chg * 4) * 224 +              \
                 (hok ? h_in : 0)) *                                        \
                    224;                                                    \
        if (hok && w_in0 >= 0 && w_in0 + 3 < 224) {                         \
          V[k][0] = *(const float4*)(cbase + w_in0);                        \
          V[k][1] = *(const float4*)(cbase + 50176 + w_in0);                \
          V[k][2] = *(const float4*)(cbase + 2 * 50176 + w_in0);            \
          V[k][3] = *(const float4*)(cbase + 3 * 50176 + w_in0);            \
        } else {                                                            \
          V[k][0] = make_float4(LD1(0, 0), LD1(0, 1), LD1(0, 2), LD1(0, 3)); \
          V[k][1] = make_float4(LD1(1, 0), LD1(1, 1), LD1(1, 2), LD1(1, 3)); \
          V[k][2] = make_float4(LD1(2, 0), LD1(2, 1), LD1(2, 2), LD1(2, 3)); \
          V[k][3] = make_float4(LD1(3, 0), LD1(3, 1), LD1(3, 2), LD1(3, 3)); \
        }                                                                   \
      }                                                                     \
    }                                                                       \
  } while (0)

  // ---- cvt + pack + ds_write into [9r][4g][34cc][8ch] ----
#define CVTW(bufsel, V)                                                     \
  do {                                                                      \
    short* lx_ = lds_x + (bufsel)*XBUF;                                     \
    _Pragma("unroll") for (int k = 0; k < 2; ++k) {                         \
      int u = t + k * 448;                                                  \
      if (u < 648) {                                                        \
        int chg = u & 7, tmp = u >> 3;                                      \
        int ccg = tmp % 9, r = tmp / 9;                                     \
        int g = chg >> 1, hs = (chg & 1) << 2;                              \
        _Pragma("unroll") for (int i = 0; i < 4; ++i) {                     \
          int cc = ccg * 4 + i;                                             \
          if (cc < 34) {                                                    \
            float a0 = ((const float*)&V[k][0])[i];                         \
            float a1 = ((const float*)&V[k][1])[i];                         \
            float a2 = ((const float*)&V[k][2])[i];                         \
            float a3 = ((const float*)&V[k][3])[i];                         \
            unsigned int p0 =                                               \
                (unsigned int)f2bfu(a0) | ((unsigned int)f2bfu(a1) << 16);  \
            unsigned int p1 =                                               \
                (unsigned int)f2bfu(a2) | ((unsigned int)f2bfu(a3) << 16);  \
            uintv2 pk = {p0, p1};                                           \
            *(uintv2*)(lx_ + (((r * 4 + g) * 34 + cc) << 3) + hs) = pk;     \
          }                                                                 \
        }                                                                   \
      }                                                                     \
    }                                                                       \
  } while (0)

  // ---- wt DMA: 2304 chunks, id = a*256 + g*64 + o -> [9a][4g][64o][8ch] ----
#define STAGE_W(ic_)                                                        \
  do {                                                                      \
    _Pragma("unroll") for (int k = 0; k < 6; ++k) {                         \
      int id = k * 448 + t;                                                 \
      if (id < 2304) {                                                      \
        int a_ = id >> 8, rem_ = id & 255;                                  \
        int g_ = rem_ >> 6, o_ = rem_ & 63;                                 \
        const short* src =                                                  \
            wtg + ((a_ * 2 + (ic_)) * 64 + o_) * 32 + g_ * 8;               \
        __builtin_amdgcn_global_load_lds(                                   \
            (const __attribute__((address_space(1))) void*)src,             \
            (__attribute__((address_space(3))) void*)(lds_w + id * 8), 16,  \
            0, 0);                                                          \
      }                                                                     \
    }                                                                       \
  } while (0)

  facc4 acc[4][2];
#pragma unroll
  for (int om = 0; om < 4; ++om)
#pragma unroll
    for (int p = 0; p < 2; ++p) {
      facc4 z = {0.f, 0.f, 0.f, 0.f};
      acc[om][p] = z;
    }

#define COMPUTE(bufsel)                                                     \
  do {                                                                      \
    const short* bx = lds_x + (bufsel)*XBUF;                                \
    __builtin_amdgcn_s_setprio(1);                                          \
    _Pragma("unroll") for (int kh = 0; kh < 3; ++kh) {                      \
      int r = wv + kh;                                                      \
      _Pragma("unroll") for (int kw = 0; kw < 3; ++kw) {                    \
        const int a_ = kh * 3 + kw;                                         \
        bhalf8 av[4];                                                       \
        _Pragma("unroll") for (int om = 0; om < 4; ++om) av[om] =           \
            *(const bhalf8*)(lds_w +                                        \
                             ((a_ * 4 + l4) * 64 + om * 16 + l15) * 8);     \
        _Pragma("unroll") for (int p = 0; p < 2; ++p) {                     \
          int tc = p * 16 + l15 + kw;                                       \
          bhalf8 bv = *(const bhalf8*)(bx + ((r * 4 + l4) * 34 + tc) * 8);  \
          _Pragma("unroll") for (int om = 0; om < 4; ++om) acc[om][p] =     \
              __builtin_amdgcn_mfma_f32_16x16x32_bf16(av[om], bv,           \
                                                      acc[om][p], 0, 0, 0); \
        }                                                                   \
      }                                                                     \
    }                                                                       \
    __builtin_amdgcn_s_setprio(0);                                          \
  } while (0)

  float4 xv[2][4];

  // ---- prologue: wt(ic0) + x(round 0) ----
  STAGE_W(0);
  LOADX(xv, 0, 0);
  CVTW(0, xv);
  asm volatile("s_waitcnt vmcnt(0)" ::: "memory");   // wt DMA landed
  asm volatile("s_waitcnt lgkmcnt(0)" ::: "memory"); // ds_writes done
  __builtin_amdgcn_sched_barrier(0);
  __builtin_amdgcn_s_barrier();
  __builtin_amdgcn_sched_barrier(0);

  // ---- 14 rounds: wc = rr>>1, ic = gray(rr); rolled (I-cache) ----
#pragma unroll 1
  for (int rr = 0; rr < 14; ++rr) {
    const int icn = ((rr + 1) ^ ((rr + 1) >> 1)) & 1;
    if (rr < 13) LOADX(xv, (rr + 1) >> 1, icn);  // early issue (T14)
    __builtin_amdgcn_sched_barrier(0);
    COMPUTE(rr & 1);

    if (rr & 1) {  // wc tile complete -> store, reset acc
      const int w0_ = (rr >> 1) * 32;
      int h = h0 + wv;
#pragma unroll
      for (int om = 0; om < 4; ++om) {
#pragma unroll
        for (int jj = 0; jj < 4; ++jj) {
          int o = om * 16 + l4 * 4 + jj;
          float bo = bias[o];
          float* op = out + ((size_t)(n * 64 + o) * 224 + h) * 224 + w0_;
#pragma unroll
          for (int p = 0; p < 2; ++p) op[p * 16 + l15] = acc[om][p][jj] + bo;
        }
      }
#pragma unroll
      for (int om = 0; om < 4; ++om)
#pragma unroll
        for (int p = 0; p < 2; ++p) {
          facc4 z = {0.f, 0.f, 0.f, 0.f};
          acc[om][p] = z;
        }
    }

    __builtin_amdgcn_s_barrier();  // readers done: idle x-buf + wt reusable
    __builtin_amdgcn_sched_barrier(0);
    if (rr < 13) {
      CVTW((rr + 1) & 1, xv);        // x regs auto-waited on use
      if (!(rr & 1)) STAGE_W(icn);   // ic changes only at even rr
      if (!(rr & 1))
        asm volatile("s_waitcnt vmcnt(0)" ::: "memory");  // wt DMA landed
      asm volatile("s_waitcnt lgkmcnt(0)" ::: "memory");  // ds_writes done
      __builtin_amdgcn_sched_barrier(0);
      __builtin_amdgcn_s_barrier();
      __builtin_amdgcn_sched_barrier(0);
    }
  }
#undef LOADX
#undef CVTW
#undef STAGE_W
#undef COMPUTE
}

extern "C" void kernel_launch(void* const* d_in, const int* in_sizes, int n_in,
                              void* d_out, int out_size, void* d_ws,
                              size_t ws_size, hipStream_t stream) {
  const float* x = (const float*)d_in[0];
  const float* wloc = (const float*)d_in[1];
  const float* wL = (const float*)d_in[2];
  const float* bloc = (const float*)d_in[3];
  const float* bro = (const float*)d_in[4];
  const float* eps_w = (const float*)d_in[5];
  const float* eps_b = (const float*)d_in[6];
  float* outp = (float*)d_out;

  short* wt = (short*)d_ws;                     // 73728 B
  float* bias = (float*)((char*)d_ws + 73728);  // 64 f32

  prep_kernel<<<16, 256, 0, stream>>>(wloc, wL, eps_w, bloc, bro, eps_b, wt,
                                      bias);
  const int dyn_lds = (2 * XBUF + 18432) * 2;  // 76032 B
  hipFuncSetAttribute((const void*)conv_sweep_kernel,
                      hipFuncAttributeMaxDynamicSharedMemorySize, dyn_lds);
  conv_sweep_kernel<<<1024, 448, dyn_lds, stream>>>(x, wt, bias, outp);
}

// Round 19
// 279.167 us; speedup vs baseline: 1.5440x; 1.5440x over previous
//
#include <hip/hip_runtime.h>
#include <hip/hip_bf16.h>
#include <stdint.h>

typedef short bhalf8 __attribute__((ext_vector_type(8)));
typedef float facc4 __attribute__((ext_vector_type(4)));
typedef unsigned int uintv2 __attribute__((ext_vector_type(2)));

static __device__ __forceinline__ unsigned short f2bfu(float f) {
  return __builtin_bit_cast(unsigned short, __float2bfloat16(f));
}

// ---------------------------------------------------------------------------
// prep: sample conv weights w = loc + L@eps (L = tril(-1)+softplus(diag)*I)
// bf16 layout wt[a=kh*3+kw][kc=i>>5][o][i&31] (R12-proven), bias.
// ---------------------------------------------------------------------------
__global__ void prep_kernel(const float* __restrict__ wloc,
                            const float* __restrict__ wL,
                            const float* __restrict__ eps_w,
                            const float* __restrict__ bloc,
                            const float* __restrict__ bro,
                            const float* __restrict__ eps_b,
                            short* __restrict__ wt, float* __restrict__ bias) {
  int t = blockIdx.x * 256 + threadIdx.x;  // t = o*64 + i
  int o = t >> 6, i = t & 63;
  int kc = i >> 5, il = i & 31;
  const float* Lp = wL + (size_t)t * 81;
  const float* ep = eps_w + (size_t)t * 9;
  const float* lp = wloc + (size_t)t * 9;
  float e[9];
#pragma unroll
  for (int b = 0; b < 9; ++b) e[b] = ep[b];
#pragma unroll
  for (int a = 0; a < 9; ++a) {
    float s = lp[a];
    for (int b = 0; b < a; ++b) s += Lp[a * 9 + b] * e[b];
    float d = Lp[a * 9 + a];
    float sp = (d > 20.f) ? d : log1pf(expf(d));
    s += sp * e[a];
    wt[((a * 2 + kc) * 64 + o) * 32 + il] = (short)f2bfu(s);
  }
  if (t < 64) {
    float d = bro[t];
    float sp = (d > 20.f) ? d : log1pf(expf(d));
    bias[t] = bloc[t] + eps_b[t] * sp;
  }
}

// ---------------------------------------------------------------------------
// fused one-pass conv (R15 verbatim — session best, 279.0 us).
// Block = 8 waves, 64o x 8r x 32px, 2 ic rounds. x staged from NCHW f32 via
// register transpose; wt DMA'd to LDS; x dbuf; T14 early-issue of round-1
// loads; direct epilogue stores. Sits at bytes_min (861 MB) / duty (3.1
// TB/s) for this kernel family — measured floor.
// ---------------------------------------------------------------------------
#define XBUF 10880  // shorts per x buffer (1360 chunks * 8)

#define LD1(cj, i)                                                    \
  ((hok && (w_in0 + (i)) >= 0 && (w_in0 + (i)) < 224)                 \
       ? cbase[(size_t)(cj)*50176 + w_in0 + (i)]                      \
       : 0.f)

__global__ __launch_bounds__(512, 4) void conv_fused_kernel(
    const float* __restrict__ x, const short* __restrict__ wtg,
    const float* __restrict__ bias, float* __restrict__ out) {
  extern __shared__ short smem[];
  short* lds_x = smem;          // 2 * 10880 shorts = 43520 B
  short* lds_w = smem + 21760;  // 2304 chunks * 8 = 18432 shorts = 36864 B

  int b0 = blockIdx.x;
  int b = (b0 & 7) * 784 + (b0 >> 3);  // bijective: 6272 % 8 == 0
  int ht = b % 28;
  int rest = b / 28;
  int wc = rest % 7, n = rest / 7;
  int h0 = ht * 8, w0 = wc * 32;
  int t = threadIdx.x, lane = t & 63, wv = t >> 6;
  int l15 = lane & 15, l4 = lane >> 4;

  // ---- x staging: load 4px x 4ch f32 into regs (units u = t + k*512) ----
#define LOADX(V, ic_)                                                       \
  do {                                                                      \
    _Pragma("unroll") for (int k = 0; k < 2; ++k) {                         \
      int u = t + k * 512;                                                  \
      if (u < 720) {                                                        \
        int chg = u & 7, tmp = u >> 3;                                      \
        int ccg = tmp % 9, r = tmp / 9;                                     \
        int h_in = h0 - 1 + r;                                              \
        bool hok = (h_in >= 0) & (h_in < 224);                              \
        int w_in0 = w0 - 1 + ccg * 4;                                       \
        const float* cbase =                                                \
            x + ((size_t)(n * 64 + (ic_)*32 + chg * 4) * 224 +              \
                 (hok ? h_in : 0)) *                                        \
                    224;                                                    \
        if (hok && w_in0 >= 0 && w_in0 + 3 < 224) {                         \
          V[k][0] = *(const float4*)(cbase + w_in0);                        \
          V[k][1] = *(const float4*)(cbase + 50176 + w_in0);                \
          V[k][2] = *(const float4*)(cbase + 2 * 50176 + w_in0);            \
          V[k][3] = *(const float4*)(cbase + 3 * 50176 + w_in0);            \
        } else {                                                            \
          V[k][0] = make_float4(LD1(0, 0), LD1(0, 1), LD1(0, 2), LD1(0, 3)); \
          V[k][1] = make_float4(LD1(1, 0), LD1(1, 1), LD1(1, 2), LD1(1, 3)); \
          V[k][2] = make_float4(LD1(2, 0), LD1(2, 1), LD1(2, 2), LD1(2, 3)); \
          V[k][3] = make_float4(LD1(3, 0), LD1(3, 1), LD1(3, 2), LD1(3, 3)); \
        }                                                                   \
      }                                                                     \
    }                                                                       \
  } while (0)

  // ---- cvt + pack + ds_write into [10r][4g][34cc][8ch] (no swizzle) ----
#define CVTW(bufsel, V)                                                     \
  do {                                                                      \
    short* lx_ = lds_x + (bufsel)*XBUF;                                     \
    _Pragma("unroll") for (int k = 0; k < 2; ++k) {                         \
      int u = t + k * 512;                                                  \
      if (u < 720) {                                                        \
        int chg = u & 7, tmp = u >> 3;                                      \
        int ccg = tmp % 9, r = tmp / 9;                                     \
        int g = chg >> 1, hs = (chg & 1) << 2;                              \
        _Pragma("unroll") for (int i = 0; i < 4; ++i) {                     \
          int cc = ccg * 4 + i;                                             \
          if (cc < 34) {                                                    \
            float a0 = ((const float*)&V[k][0])[i];                         \
            float a1 = ((const float*)&V[k][1])[i];                         \
            float a2 = ((const float*)&V[k][2])[i];                         \
            float a3 = ((const float*)&V[k][3])[i];                         \
            unsigned int p0 =                                               \
                (unsigned int)f2bfu(a0) | ((unsigned int)f2bfu(a1) << 16);  \
            unsigned int p1 =                                               \
                (unsigned int)f2bfu(a2) | ((unsigned int)f2bfu(a3) << 16);  \
            uintv2 pk = {p0, p1};                                           \
            *(uintv2*)(lx_ + (((r * 4 + g) * 34 + cc) << 3) + hs) = pk;     \
          }                                                                 \
        }                                                                   \
      }                                                                     \
    }                                                                       \
  } while (0)

  // ---- wt DMA: 2304 chunks, id = a*256 + g*64 + o (R12-proven) ----
#define STAGE_W(ic_)                                                        \
  do {                                                                      \
    _Pragma("unroll") for (int k = 0; k < 5; ++k) {                         \
      int id = k * 512 + t;                                                 \
      if (id < 2304) {                                                      \
        int a_ = id >> 8, rem_ = id & 255;                                  \
        int g_ = rem_ >> 6, o_ = rem_ & 63;                                 \
        const short* src =                                                  \
            wtg + ((a_ * 2 + (ic_)) * 64 + o_) * 32 + g_ * 8;               \
        __builtin_amdgcn_global_load_lds(                                   \
            (const __attribute__((address_space(1))) void*)src,             \
            (__attribute__((address_space(3))) void*)(lds_w +               \
                                                      (k * 512 + wv * 64) * \
                                                          8),               \
            16, 0, 0);                                                      \
      }                                                                     \
    }                                                                       \
  } while (0)

  facc4 acc[4][2];
#pragma unroll
  for (int om = 0; om < 4; ++om)
#pragma unroll
    for (int p = 0; p < 2; ++p) {
      facc4 z = {0.f, 0.f, 0.f, 0.f};
      acc[om][p] = z;
    }

#define COMPUTE(bufsel)                                                     \
  do {                                                                      \
    const short* bx = lds_x + (bufsel)*XBUF;                                \
    __builtin_amdgcn_s_setprio(1);                                          \
    _Pragma("unroll") for (int kh = 0; kh < 3; ++kh) {                      \
      int r = wv + kh;                                                      \
      _Pragma("unroll") for (int kw = 0; kw < 3; ++kw) {                    \
        const int a_ = kh * 3 + kw;                                         \
        bhalf8 av[4];                                                       \
        _Pragma("unroll") for (int om = 0; om < 4; ++om) av[om] =           \
            *(const bhalf8*)(lds_w +                                        \
                             ((a_ * 4 + l4) * 64 + om * 16 + l15) * 8);     \
        _Pragma("unroll") for (int p = 0; p < 2; ++p) {                     \
          int tc = p * 16 + l15 + kw;                                       \
          bhalf8 bv = *(const bhalf8*)(bx + ((r * 4 + l4) * 34 + tc) * 8);  \
          _Pragma("unroll") for (int om = 0; om < 4; ++om) acc[om][p] =     \
              __builtin_amdgcn_mfma_f32_16x16x32_bf16(av[om], bv,           \
                                                      acc[om][p], 0, 0, 0); \
        }                                                                   \
      }                                                                     \
    }                                                                       \
    __builtin_amdgcn_s_setprio(0);                                          \
  } while (0)

  float4 xv[2][4];

  // ---- prologue: stage wt(ic0) + x(ic0) ----
  STAGE_W(0);
  LOADX(xv, 0);
  CVTW(0, xv);
  asm volatile("s_waitcnt vmcnt(0)" ::: "memory");  // wt DMA landed
  __syncthreads();                                  // ds_writes visible

  // ---- round 0: issue round-1 x loads EARLY (hide under MFMA) ----
  LOADX(xv, 1);
  __builtin_amdgcn_sched_barrier(0);
  COMPUTE(0);
  __builtin_amdgcn_s_barrier();  // all reads of buf0 + wt(ic0) done
  __builtin_amdgcn_sched_barrier(0);
  STAGE_W(1);
  CVTW(1, xv);  // xv landed during COMPUTE(0)
  asm volatile("s_waitcnt vmcnt(0)" ::: "memory");  // wt(ic1) landed
  __syncthreads();
  COMPUTE(1);

#undef LOADX
#undef CVTW
#undef STAGE_W
#undef COMPUTE

  // ---- epilogue: direct stores (R12-proven) ----
  int h = h0 + wv;
#pragma unroll
  for (int om = 0; om < 4; ++om) {
#pragma unroll
    for (int jj = 0; jj < 4; ++jj) {
      int o = om * 16 + l4 * 4 + jj;
      float bo = bias[o];
      float* op = out + ((size_t)(n * 64 + o) * 224 + h) * 224 + w0;
#pragma unroll
      for (int p = 0; p < 2; ++p) op[p * 16 + l15] = acc[om][p][jj] + bo;
    }
  }
}

extern "C" void kernel_launch(void* const* d_in, const int* in_sizes, int n_in,
                              void* d_out, int out_size, void* d_ws,
                              size_t ws_size, hipStream_t stream) {
  const float* x = (const float*)d_in[0];
  const float* wloc = (const float*)d_in[1];
  const float* wL = (const float*)d_in[2];
  const float* bloc = (const float*)d_in[3];
  const float* bro = (const float*)d_in[4];
  const float* eps_w = (const float*)d_in[5];
  const float* eps_b = (const float*)d_in[6];
  float* outp = (float*)d_out;

  short* wt = (short*)d_ws;                     // 73728 B
  float* bias = (float*)((char*)d_ws + 73728);  // 64 f32

  prep_kernel<<<16, 256, 0, stream>>>(wloc, wL, eps_w, bloc, bro, eps_b, wt,
                                      bias);
  const int dyn_lds = (21760 + 18432) * 2;  // 80384 B
  hipFuncSetAttribute((const void*)conv_fused_kernel,
                      hipFuncAttributeMaxDynamicSharedMemorySize, dyn_lds);
  conv_fused_kernel<<<6272, 512, dyn_lds, stream>>>(x, wt, bias, outp);
}